// Round 1
// baseline (2301.460 us; speedup 1.0000x reference)
//
#include <hip/hip_runtime.h>
#include <hip/hip_bf16.h>

// Problem dims
constexpr int kS = 512;
constexpr int kB = 64;
constexpr int kE = 300;
constexpr int kH = 256;
constexpr int kM = 512;
constexpr int kC = 20;

__device__ __forceinline__ float fast_tanh(float z) {
    z = fminf(15.f, fmaxf(-15.f, z));
    float e = __expf(2.f * z);
    return 1.f - 2.f / (e + 1.f);
}

// ---------------------------------------------------------------------------
// K1: emb gather + projections:  X[pos][h] = emb[inp[pos]] . W_s{l,r}[h,:] + b
// grid (1024 pos-tiles, 4 col-tiles), 256 threads. Tile: 32 pos x 128 cols.
// ---------------------------------------------------------------------------
__global__ __launch_bounds__(256) void proj_kernel(
    const int* __restrict__ inp, const float* __restrict__ emb_table,
    const float* __restrict__ W_sl_w, const float* __restrict__ W_sl_b,
    const float* __restrict__ W_sr_w, const float* __restrict__ W_sr_b,
    float* __restrict__ X_ls, float* __restrict__ X_rs)
{
    __shared__ float a[32][304];
    __shared__ int rows[32];
    const int tid = threadIdx.x;
    const int pos0 = blockIdx.x * 32;
    const int mt = blockIdx.y;

    if (tid < 32) rows[tid] = inp[pos0 + tid];
    __syncthreads();
    // stage emb tile: 32 rows x 75 float4 (E=300)
    for (int i = tid; i < 32 * 75; i += 256) {
        int r = i / 75, q = i - r * 75;
        float4 v = *(const float4*)&emb_table[rows[r] * kE + q * 4];
        *(float4*)&a[r][q * 4] = v;
    }
    __syncthreads();

    const float* Wp = (mt < 2) ? W_sl_w : W_sr_w;
    const float* bp = (mt < 2) ? W_sl_b : W_sr_b;
    float* Xp = (mt < 2) ? X_ls : X_rs;
    const int colb = (mt & 1) * 128;

    const int cg = tid & 31;   // 32 col groups * 4 cols = 128
    const int pg = tid >> 5;   // 8 pos groups * 4 pos = 32

    float acc[4][4];
#pragma unroll
    for (int i = 0; i < 4; ++i)
#pragma unroll
        for (int j = 0; j < 4; ++j) acc[i][j] = 0.f;

    const float* w0 = Wp + (colb + cg * 4) * kE;
    for (int k4 = 0; k4 < 75; ++k4) {
        float4 w[4];
#pragma unroll
        for (int j = 0; j < 4; ++j) w[j] = *(const float4*)&w0[j * kE + k4 * 4];
#pragma unroll
        for (int i = 0; i < 4; ++i) {
            float4 av = *(const float4*)&a[pg * 4 + i][k4 * 4];
#pragma unroll
            for (int j = 0; j < 4; ++j)
                acc[i][j] += av.x * w[j].x + av.y * w[j].y + av.z * w[j].z + av.w * w[j].w;
        }
    }
    float4 bv = *(const float4*)&bp[colb + cg * 4];
#pragma unroll
    for (int i = 0; i < 4; ++i) {
        int pos = pos0 + pg * 4 + i;
        float4 o;
        o.x = acc[i][0] + bv.x;
        o.y = acc[i][1] + bv.y;
        o.z = acc[i][2] + bv.z;
        o.w = acc[i][3] + bv.w;
        *(float4*)&Xp[pos * kH + colb + cg * 4] = o;
    }
}

// ---------------------------------------------------------------------------
// K2: bidirectional scan. 128 blocks (dir*64 + b), 512 threads (2 k-halves
// per h). W row halves live in 32 float4 VGPRs per thread. c broadcast in LDS.
// X is overwritten in place with the scan outputs.
// ---------------------------------------------------------------------------
__global__ __launch_bounds__(512, 2) void scan_kernel(
    const float* __restrict__ W_l, const float* __restrict__ b_l,
    const float* __restrict__ W_r, const float* __restrict__ b_r,
    const float* __restrict__ c_l0, const float* __restrict__ c_r0,
    float* __restrict__ X_ls, float* __restrict__ X_rs)
{
    const int bid = blockIdx.x;
    const int dir = bid >> 6;   // 0 = left-to-right, 1 = right-to-left
    const int b = bid & 63;
    const int tid = threadIdx.x;
    const int h = tid & 255;
    const int half = tid >> 8;

    const float* W = dir ? W_r : W_l;
    const float* bias = dir ? b_r : b_l;
    float* X = dir ? X_rs : X_ls;

    __shared__ float c_sh[256];
    __shared__ float part[2][256];

    float4 w[32];
#pragma unroll
    for (int i = 0; i < 32; ++i)
        w[i] = *(const float4*)&W[h * kH + half * 128 + i * 4];

    float wb = 0.f;
    if (half == 0) {
        wb = bias[h];
        c_sh[h] = (dir ? c_r0 : c_l0)[h];
    }
    __syncthreads();

    for (int step = 0; step < kS; ++step) {
        const int s = dir ? (kS - 1 - step) : step;
        const int xi = (s * kB + b) * kH + h;
        float x = 0.f;
        if (half == 0) x = X[xi];   // issued early; latency hidden by the dot

        float a0 = 0.f, a1 = 0.f, a2 = 0.f, a3 = 0.f;
        const float4* cs = (const float4*)&c_sh[half * 128];
#pragma unroll
        for (int i = 0; i < 32; ++i) {
            float4 cv = cs[i];
            a0 += w[i].x * cv.x;
            a1 += w[i].y * cv.y;
            a2 += w[i].z * cv.z;
            a3 += w[i].w * cv.w;
        }
        part[half][h] = (a0 + a1) + (a2 + a3);
        __syncthreads();
        if (half == 0) {
            float z = part[0][h] + part[1][h] + wb + x;
            float c = fast_tanh(z);
            c_sh[h] = c;
            X[xi] = c;
        }
        __syncthreads();
    }
}

// ---------------------------------------------------------------------------
// K3: cat(c_ls | emb | c_rs) . max_w^T, running max over 16 s per block.
// tanh is monotone -> store max of pre-activations (bias/tanh applied in K4).
// grid (64 b, 4 m-tiles, 32 s-chunks), 256 threads. Tile: 16 s x 128 m.
// ---------------------------------------------------------------------------
__global__ __launch_bounds__(256) void maxlayer_kernel(
    const int* __restrict__ inp, const float* __restrict__ emb_table,
    const float* __restrict__ X_ls, const float* __restrict__ X_rs,
    const float* __restrict__ max_w, float* __restrict__ part_max)
{
    __shared__ float a[16][816];
    __shared__ int rows[16];
    __shared__ float red[4][128];
    const int tid = threadIdx.x;
    const int b = blockIdx.x;
    const int mt = blockIdx.y;
    const int sc = blockIdx.z;
    const int s0 = sc * 16;

    if (tid < 16) rows[tid] = inp[(s0 + tid) * kB + b];
    __syncthreads();
    // seg1 (c_ls @ [0,256)) and seg3 (c_rs @ [556,812)): 16 rows x 64 f4 each
    for (int i = tid; i < 16 * 64; i += 256) {
        int r = i >> 6, q = i & 63;
        int pos = (s0 + r) * kB + b;
        *(float4*)&a[r][q * 4] = *(const float4*)&X_ls[pos * kH + q * 4];
        *(float4*)&a[r][556 + q * 4] = *(const float4*)&X_rs[pos * kH + q * 4];
    }
    // seg2 (emb @ [256,556)): 16 rows x 75 f4
    for (int i = tid; i < 16 * 75; i += 256) {
        int r = i / 75, q = i - r * 75;
        *(float4*)&a[r][256 + q * 4] = *(const float4*)&emb_table[rows[r] * kE + q * 4];
    }
    __syncthreads();

    const int cg = tid & 63;   // 64 groups * 2 cols = 128
    const int rg = tid >> 6;   // 4 groups * 4 rows = 16
    const int c0 = mt * 128 + cg * 2;

    float acc[4][2];
#pragma unroll
    for (int i = 0; i < 4; ++i) { acc[i][0] = 0.f; acc[i][1] = 0.f; }

    const float* w0 = max_w + c0 * 812;
    for (int k4 = 0; k4 < 203; ++k4) {
        float4 wa = *(const float4*)&w0[k4 * 4];
        float4 wbv = *(const float4*)&w0[812 + k4 * 4];
#pragma unroll
        for (int i = 0; i < 4; ++i) {
            float4 av = *(const float4*)&a[rg * 4 + i][k4 * 4];
            acc[i][0] += av.x * wa.x + av.y * wa.y + av.z * wa.z + av.w * wa.w;
            acc[i][1] += av.x * wbv.x + av.y * wbv.y + av.z * wbv.z + av.w * wbv.w;
        }
    }
    float m0 = fmaxf(fmaxf(acc[0][0], acc[1][0]), fmaxf(acc[2][0], acc[3][0]));
    float m1 = fmaxf(fmaxf(acc[0][1], acc[1][1]), fmaxf(acc[2][1], acc[3][1]));
    red[rg][cg * 2] = m0;
    red[rg][cg * 2 + 1] = m1;
    __syncthreads();
    if (tid < 128) {
        float v = fmaxf(fmaxf(red[0][tid], red[1][tid]), fmaxf(red[2][tid], red[3][tid]));
        part_max[(sc * kB + b) * kM + mt * 128 + tid] = v;
    }
}

// ---------------------------------------------------------------------------
// K4: combine 32 partial maxes, tanh(. + max_b), doc layer, log_softmax.
// 64 blocks (one per batch), 256 threads.
// ---------------------------------------------------------------------------
__global__ __launch_bounds__(256) void final_kernel(
    const float* __restrict__ part_max, const float* __restrict__ max_b,
    const float* __restrict__ doc_w, const float* __restrict__ doc_b,
    float* __restrict__ out)
{
    const int b = blockIdx.x;
    const int t = threadIdx.x;
    __shared__ float ym[kM];
    __shared__ float red[160];
    __shared__ float logits[kC];

    for (int m = t; m < kM; m += 256) {
        float v = -1e30f;
        for (int ch = 0; ch < 32; ++ch)
            v = fmaxf(v, part_max[(ch * kB + b) * kM + m]);
        ym[m] = fast_tanh(v + max_b[m]);
    }
    __syncthreads();
    if (t < 160) {
        int c = t >> 3, kg = t & 7;
        float s = 0.f;
        const float* wr = doc_w + c * kM + kg * 64;
        const float* yr = ym + kg * 64;
        for (int k = 0; k < 64; ++k) s += yr[k] * wr[k];
        red[t] = s;
    }
    __syncthreads();
    if (t < kC) {
        float s = doc_b[t];
        for (int kg = 0; kg < 8; ++kg) s += red[t * 8 + kg];
        logits[t] = s;
    }
    __syncthreads();
    if (t == 0) {
        float mx = logits[0];
        for (int c = 1; c < kC; ++c) mx = fmaxf(mx, logits[c]);
        float se = 0.f;
        for (int c = 0; c < kC; ++c) se += __expf(logits[c] - mx);
        float lse = mx + __logf(se);
        for (int c = 0; c < kC; ++c) out[b * kC + c] = logits[c] - lse;
    }
}

extern "C" void kernel_launch(void* const* d_in, const int* in_sizes, int n_in,
                              void* d_out, int out_size, void* d_ws, size_t ws_size,
                              hipStream_t stream) {
    const int* inp = (const int*)d_in[0];
    const float* emb_table = (const float*)d_in[1];
    const float* c_l0 = (const float*)d_in[2];
    const float* c_r0 = (const float*)d_in[3];
    const float* W_l_w = (const float*)d_in[4];
    const float* W_l_b = (const float*)d_in[5];
    const float* W_r_w = (const float*)d_in[6];
    const float* W_r_b = (const float*)d_in[7];
    const float* W_sl_w = (const float*)d_in[8];
    const float* W_sl_b = (const float*)d_in[9];
    const float* W_sr_w = (const float*)d_in[10];
    const float* W_sr_b = (const float*)d_in[11];
    const float* max_w = (const float*)d_in[12];
    const float* max_b = (const float*)d_in[13];
    const float* doc_w = (const float*)d_in[14];
    const float* doc_b = (const float*)d_in[15];
    float* out = (float*)d_out;

    float* ws = (float*)d_ws;
    float* X_ls = ws;                                  // S*B*H f32
    float* X_rs = X_ls + (size_t)kS * kB * kH;         // S*B*H f32
    float* part_max = X_rs + (size_t)kS * kB * kH;     // 32*B*M f32

    proj_kernel<<<dim3(kS * kB / 32, 4), 256, 0, stream>>>(
        inp, emb_table, W_sl_w, W_sl_b, W_sr_w, W_sr_b, X_ls, X_rs);
    scan_kernel<<<128, 512, 0, stream>>>(
        W_l_w, W_l_b, W_r_w, W_r_b, c_l0, c_r0, X_ls, X_rs);
    maxlayer_kernel<<<dim3(kB, 4, 32), 256, 0, stream>>>(
        inp, emb_table, X_ls, X_rs, max_w, part_max);
    final_kernel<<<kB, 256, 0, stream>>>(part_max, max_b, doc_w, doc_b, out);
}

// Round 4
// 1007.336 us; speedup vs baseline: 2.2847x; 2.2847x over previous
//
#include <hip/hip_runtime.h>
#include <hip/hip_bf16.h>

// Problem dims
constexpr int kS = 512;
constexpr int kB = 64;
constexpr int kE = 300;
constexpr int kH = 256;
constexpr int kM = 512;
constexpr int kC = 20;

typedef short s16x8 __attribute__((ext_vector_type(8)));
typedef float f32x4 __attribute__((ext_vector_type(4)));
typedef unsigned short u16x4 __attribute__((ext_vector_type(4)));

__device__ __forceinline__ float fast_tanh(float z) {
    z = fminf(15.f, fmaxf(-15.f, z));
    float e = __expf(2.f * z);
    return 1.f - 2.f / (e + 1.f);
}

__device__ __forceinline__ unsigned short f2bf(float f) {
    __hip_bfloat16 h = __float2bfloat16(f);
    return *(unsigned short*)&h;
}
__device__ __forceinline__ float bf2f(unsigned short u) {
    __hip_bfloat16 h = *(__hip_bfloat16*)&u;
    return __bfloat162float(h);
}

// ---------------------------------------------------------------------------
// cat layout, per row (row = b*512 + s), 832 bf16 cols:
//   [0,256)   : proj writes X_l pre-acts; scan dir0 reads x / overwrites c_ls
//   [256,556) : emb (gather)
//   [556,576) : zeros (gather; proj A K-pad) -> scan dir1 overwrites with c_rs
//   [556,812) : c_rs after scan dir1
//   [576,832) : proj writes X_r pre-acts (col 576+h); scan dir1 reads them
//   [812,832) : X_r residue after scan; killed by Wmax zero cols
// ---------------------------------------------------------------------------

// K0a: weights -> bf16, zero-padded. Wmax [512][832], Wproj [512][320].
__global__ __launch_bounds__(256) void prepw_kernel(
    const float* __restrict__ max_w,
    const float* __restrict__ wsl, const float* __restrict__ wsr,
    unsigned short* __restrict__ Wmax, unsigned short* __restrict__ Wproj)
{
    int idx = blockIdx.x * 256 + threadIdx.x;
    if (idx < 512 * 832) {
        int r = idx / 832, c = idx - r * 832;
        Wmax[idx] = f2bf(c < 812 ? max_w[r * 812 + c] : 0.f);
    }
    if (idx < 512 * 320) {
        int r = idx / 320, c = idx - r * 320;
        float v = 0.f;
        if (c < 300) v = (r < 256) ? wsl[r * 300 + c] : wsr[(r - 256) * 300 + c];
        Wproj[idx] = f2bf(v);
    }
}

// K0b: gather emb rows into cat cols [256,556); zero [556,576) and [812,832).
__global__ __launch_bounds__(128) void gather_kernel(
    const int* __restrict__ inp, const float* __restrict__ emb_table,
    unsigned short* __restrict__ cat)
{
    const int row = blockIdx.x;          // b*512 + s
    const int b = row >> 9, s = row & 511;
    const int t = threadIdx.x;
    unsigned short* dst = cat + (size_t)row * 832;
    const int v = inp[s * kB + b];
    const float* src = emb_table + (size_t)v * kE;
    if (t < 75) {
        float4 f = *(const float4*)&src[t * 4];
        u16x4 o = { f2bf(f.x), f2bf(f.y), f2bf(f.z), f2bf(f.w) };
        *(u16x4*)&dst[256 + t * 4] = o;
    } else if (t < 80) {
        u16x4 z = { 0, 0, 0, 0 };
        *(u16x4*)&dst[556 + (t - 75) * 4] = z;
    } else if (t < 85) {
        u16x4 z = { 0, 0, 0, 0 };
        *(u16x4*)&dst[812 + (t - 80) * 4] = z;
    }
}

// K1: proj GEMM (MFMA bf16), in-place epilogue into cat.
// A = cat cols [256,576) (lda 832), B = Wproj [512][320]. 128x128 tile,
// 4 waves each 64x64, K=320 in 10 steps of 32. LDS stride 40.
// Staging: 2 threads/row, each stores TWO float4s (16 shorts) -> full 32-col
// K-slice per row. (Round-2/3 bug: one float4 = 8 shorts, half tile stale.)
__global__ __launch_bounds__(256) void proj_mfma_kernel(
    unsigned short* cat,
    const unsigned short* __restrict__ Wproj,
    const float* __restrict__ b_sl, const float* __restrict__ b_sr)
{
    __shared__ unsigned short As[128 * 40];
    __shared__ unsigned short Bs[128 * 40];
    const int tid = threadIdx.x;
    const int row0 = blockIdx.x * 128;
    const int col0 = blockIdx.y * 128;
    const int lane = tid & 63;
    const int wave = tid >> 6;
    const int wr = (wave >> 1) * 64, wc = (wave & 1) * 64;
    const int l15 = lane & 15, lk = (lane >> 4) * 8;
    const int srow = tid >> 1;
    const int sh = (tid & 1) * 16;        // shorts offset {0,16}; covers +16

    const unsigned short* Ag = cat + (size_t)(row0 + srow) * 832 + 256 + sh;
    const unsigned short* Bg = Wproj + (size_t)(col0 + srow) * 320 + sh;

    f32x4 acc[4][4] = {};
    float4 av0 = *(const float4*)Ag;
    float4 av1 = *(const float4*)(Ag + 8);
    float4 bv0 = *(const float4*)Bg;
    float4 bv1 = *(const float4*)(Bg + 8);

    for (int kk = 0; kk < 10; ++kk) {
        __syncthreads();
        *(float4*)&As[srow * 40 + sh] = av0;
        *(float4*)&As[srow * 40 + sh + 8] = av1;
        *(float4*)&Bs[srow * 40 + sh] = bv0;
        *(float4*)&Bs[srow * 40 + sh + 8] = bv1;
        __syncthreads();
        if (kk < 9) {
            av0 = *(const float4*)(Ag + (kk + 1) * 32);
            av1 = *(const float4*)(Ag + (kk + 1) * 32 + 8);
            bv0 = *(const float4*)(Bg + (kk + 1) * 32);
            bv1 = *(const float4*)(Bg + (kk + 1) * 32 + 8);
        }
        s16x8 af[4], bf[4];
#pragma unroll
        for (int f = 0; f < 4; ++f) {
            af[f] = *(const s16x8*)&As[(wr + f * 16 + l15) * 40 + lk];
            bf[f] = *(const s16x8*)&Bs[(wc + f * 16 + l15) * 40 + lk];
        }
#pragma unroll
        for (int i = 0; i < 4; ++i)
#pragma unroll
            for (int j = 0; j < 4; ++j)
                acc[i][j] = __builtin_amdgcn_mfma_f32_16x16x32_bf16(af[i], bf[j], acc[i][j], 0, 0, 0);
    }

    const int rbase = row0 + wr + (lane >> 4) * 4;
#pragma unroll
    for (int j = 0; j < 4; ++j) {
        const int col = col0 + wc + j * 16 + l15;           // output h' in [0,512)
        const float bias = (col < kH) ? b_sl[col] : b_sr[col - kH];
        const int ccol = (col < kH) ? col : (320 + col);    // cat col: [0,256) or [576,832)
#pragma unroll
        for (int i = 0; i < 4; ++i) {
#pragma unroll
            for (int r = 0; r < 4; ++r) {
                const int row = rbase + i * 16 + r;
                cat[(size_t)row * 832 + ccol] = f2bf(acc[i][j][r] + bias);
            }
        }
    }
}

// K2: bidirectional scan (fp32 recurrence), in-place on cat.
// 128 blocks (dir*64+b), 512 threads. dir0: x@col h -> c@col h.
// dir1: x@col 576+h -> c@col 556+h.
__global__ __launch_bounds__(512, 2) void scan_kernel(
    const float* __restrict__ W_l, const float* __restrict__ b_l,
    const float* __restrict__ W_r, const float* __restrict__ b_r,
    const float* __restrict__ c_l0, const float* __restrict__ c_r0,
    unsigned short* cat)
{
    const int bid = blockIdx.x;
    const int dir = bid >> 6;
    const int b = bid & 63;
    const int tid = threadIdx.x;
    const int h = tid & 255;
    const int half = tid >> 8;

    const float* W = dir ? W_r : W_l;
    const float* bias = dir ? b_r : b_l;
    const int xoff = dir ? 576 : 0;
    const int coff = dir ? 556 : 0;

    __shared__ float c_sh[256];
    __shared__ float part[2][256];

    float4 w[32];
#pragma unroll
    for (int i = 0; i < 32; ++i)
        w[i] = *(const float4*)&W[h * kH + half * 128 + i * 4];

    float wb = 0.f;
    if (half == 0) {
        wb = bias[h];
        c_sh[h] = (dir ? c_r0 : c_l0)[h];
    }
    __syncthreads();

    for (int step = 0; step < kS; ++step) {
        const int s = dir ? (kS - 1 - step) : step;
        const size_t ri = (size_t)(b * kS + s);
        float x = 0.f;
        if (half == 0) x = bf2f(cat[ri * 832 + xoff + h]);  // early issue

        float a0 = 0.f, a1 = 0.f, a2 = 0.f, a3 = 0.f;
        const float4* cs = (const float4*)&c_sh[half * 128];
#pragma unroll
        for (int i = 0; i < 32; ++i) {
            float4 cv = cs[i];
            a0 += w[i].x * cv.x;
            a1 += w[i].y * cv.y;
            a2 += w[i].z * cv.z;
            a3 += w[i].w * cv.w;
        }
        part[half][h] = (a0 + a1) + (a2 + a3);
        __syncthreads();
        if (half == 0) {
            float z = part[0][h] + part[1][h] + wb + x;
            float c = fast_tanh(z);
            c_sh[h] = c;
            cat[ri * 832 + coff + h] = f2bf(c);
        }
        __syncthreads();
    }
}

// K3: maxlayer GEMM (MFMA bf16) + per-column max over the 128-row tile.
// A = cat rows [b*512+sc*128,+128) K=832; B = Wmax rows [mt*128,+128).
__global__ __launch_bounds__(256) void maxlayer_mfma_kernel(
    const unsigned short* __restrict__ cat,
    const unsigned short* __restrict__ Wmax,
    float* __restrict__ part_max)
{
    __shared__ unsigned short As[128 * 40];
    __shared__ unsigned short Bs[128 * 40];
    __shared__ float red[2][128];
    const int tid = threadIdx.x;
    const int mt = blockIdx.x, sc = blockIdx.y, b = blockIdx.z;
    const int row0 = b * 512 + sc * 128;
    const int col0 = mt * 128;
    const int lane = tid & 63;
    const int wave = tid >> 6;
    const int wrow = wave >> 1;
    const int wr = wrow * 64, wc = (wave & 1) * 64;
    const int l15 = lane & 15, lk = (lane >> 4) * 8;
    const int srow = tid >> 1;
    const int sh = (tid & 1) * 16;

    const unsigned short* Ag = cat + (size_t)(row0 + srow) * 832 + sh;
    const unsigned short* Bg = Wmax + (size_t)(col0 + srow) * 832 + sh;

    f32x4 acc[4][4] = {};
    float4 av0 = *(const float4*)Ag;
    float4 av1 = *(const float4*)(Ag + 8);
    float4 bv0 = *(const float4*)Bg;
    float4 bv1 = *(const float4*)(Bg + 8);

    for (int kk = 0; kk < 26; ++kk) {
        __syncthreads();
        *(float4*)&As[srow * 40 + sh] = av0;
        *(float4*)&As[srow * 40 + sh + 8] = av1;
        *(float4*)&Bs[srow * 40 + sh] = bv0;
        *(float4*)&Bs[srow * 40 + sh + 8] = bv1;
        __syncthreads();
        if (kk < 25) {
            av0 = *(const float4*)(Ag + (kk + 1) * 32);
            av1 = *(const float4*)(Ag + (kk + 1) * 32 + 8);
            bv0 = *(const float4*)(Bg + (kk + 1) * 32);
            bv1 = *(const float4*)(Bg + (kk + 1) * 32 + 8);
        }
        s16x8 af[4], bf[4];
#pragma unroll
        for (int f = 0; f < 4; ++f) {
            af[f] = *(const s16x8*)&As[(wr + f * 16 + l15) * 40 + lk];
            bf[f] = *(const s16x8*)&Bs[(wc + f * 16 + l15) * 40 + lk];
        }
#pragma unroll
        for (int i = 0; i < 4; ++i)
#pragma unroll
            for (int j = 0; j < 4; ++j)
                acc[i][j] = __builtin_amdgcn_mfma_f32_16x16x32_bf16(af[i], bf[j], acc[i][j], 0, 0, 0);
    }

#pragma unroll
    for (int j = 0; j < 4; ++j) {
        float m = -1e30f;
#pragma unroll
        for (int i = 0; i < 4; ++i)
#pragma unroll
            for (int r = 0; r < 4; ++r) m = fmaxf(m, acc[i][j][r]);
        m = fmaxf(m, __shfl_xor(m, 16));
        m = fmaxf(m, __shfl_xor(m, 32));
        if (lane < 16) red[wrow][wc + j * 16 + lane] = m;
    }
    __syncthreads();
    if (tid < 128) {
        float v = fmaxf(red[0][tid], red[1][tid]);
        part_max[((size_t)(b * 4 + sc)) * kM + col0 + tid] = v;
    }
}

// K4: combine 4 partial maxes, tanh(. + max_b), doc layer, log_softmax.
__global__ __launch_bounds__(256) void final_kernel(
    const float* __restrict__ part_max, const float* __restrict__ max_b,
    const float* __restrict__ doc_w, const float* __restrict__ doc_b,
    float* __restrict__ out)
{
    const int b = blockIdx.x;
    const int t = threadIdx.x;
    __shared__ float ym[kM];
    __shared__ float red[160];
    __shared__ float logits[kC];

    for (int m = t; m < kM; m += 256) {
        float v = -1e30f;
        for (int ch = 0; ch < 4; ++ch)
            v = fmaxf(v, part_max[((size_t)(b * 4 + ch)) * kM + m]);
        ym[m] = fast_tanh(v + max_b[m]);
    }
    __syncthreads();
    if (t < 160) {
        int c = t >> 3, kg = t & 7;
        float s = 0.f;
        const float* wr = doc_w + c * kM + kg * 64;
        const float* yr = ym + kg * 64;
        for (int k = 0; k < 64; ++k) s += yr[k] * wr[k];
        red[t] = s;
    }
    __syncthreads();
    if (t < kC) {
        float s = doc_b[t];
        for (int kg = 0; kg < 8; ++kg) s += red[t * 8 + kg];
        logits[t] = s;
    }
    __syncthreads();
    if (t == 0) {
        float mx = logits[0];
        for (int c = 1; c < kC; ++c) mx = fmaxf(mx, logits[c]);
        float se = 0.f;
        for (int c = 0; c < kC; ++c) se += __expf(logits[c] - mx);
        float lse = mx + __logf(se);
        for (int c = 0; c < kC; ++c) out[b * kC + c] = logits[c] - lse;
    }
}

extern "C" void kernel_launch(void* const* d_in, const int* in_sizes, int n_in,
                              void* d_out, int out_size, void* d_ws, size_t ws_size,
                              hipStream_t stream) {
    const int* inp = (const int*)d_in[0];
    const float* emb_table = (const float*)d_in[1];
    const float* c_l0 = (const float*)d_in[2];
    const float* c_r0 = (const float*)d_in[3];
    const float* W_l_w = (const float*)d_in[4];
    const float* W_l_b = (const float*)d_in[5];
    const float* W_r_w = (const float*)d_in[6];
    const float* W_r_b = (const float*)d_in[7];
    const float* W_sl_w = (const float*)d_in[8];
    const float* W_sl_b = (const float*)d_in[9];
    const float* W_sr_w = (const float*)d_in[10];
    const float* W_sr_b = (const float*)d_in[11];
    const float* max_w = (const float*)d_in[12];
    const float* max_b = (const float*)d_in[13];
    const float* doc_w = (const float*)d_in[14];
    const float* doc_b = (const float*)d_in[15];
    float* out = (float*)d_out;

    // Workspace: 56,229,888 bytes total.
    char* w = (char*)d_ws;
    unsigned short* cat   = (unsigned short*)(w);                 // 32768*832*2 = 54,525,952
    unsigned short* Wmax  = (unsigned short*)(w + 54525952);      // 512*832*2   =    851,968
    unsigned short* Wproj = (unsigned short*)(w + 55377920);      // 512*320*2   =    327,680
    float* part_max       = (float*)(w + 55705600);               // 4*64*512*4  =    524,288

    prepw_kernel<<<(512 * 832 + 255) / 256, 256, 0, stream>>>(
        max_w, W_sl_w, W_sr_w, Wmax, Wproj);
    gather_kernel<<<kS * kB, 128, 0, stream>>>(inp, emb_table, cat);
    proj_mfma_kernel<<<dim3(256, 4), 256, 0, stream>>>(
        cat, Wproj, W_sl_b, W_sr_b);
    scan_kernel<<<128, 512, 0, stream>>>(
        W_l_w, W_l_b, W_r_w, W_r_b, c_l0, c_r0, cat);
    maxlayer_mfma_kernel<<<dim3(4, 4, 64), 256, 0, stream>>>(cat, Wmax, part_max);
    final_kernel<<<kB, 256, 0, stream>>>(part_max, max_b, doc_w, doc_b, out);
}